// Round 1
// baseline (150.715 us; speedup 1.0000x reference)
//
#include <hip/hip_runtime.h>
#include <hip/hip_bf16.h>

// Problem constants (from reference)
#define N_SRC 50000
#define N_DST 10000
#define KNBR  32
#define IN_F  256
#define OUT_F 128
#define NHEAD 8
#define LDIM  10
#define ATTN_IN (2*OUT_F)          // 256
#define ATTN_OUT (OUT_F*NHEAD)     // 1024

// Workspace layout (in floats):
//   [0..255]    w_comb (256)
//   [256]       c0
//   [512 ..]    h_src   (N_SRC*OUT_F = 6,400,000)
//   [6400512..] self0   (N_DST*OUT_F = 1,280,000)
#define WS_WCOMB 0
#define WS_C0    256
#define WS_HSRC  512
#define WS_SELF0 (512 + N_SRC*OUT_F)

// Output layout (floats): rst (N_DST*OUT_F) | cent_l (N_DST*LDIM) | labels_ori[:N_DST] (N_DST*LDIM)
#define OUT_RST_SZ (N_DST*OUT_F)
#define OUT_CENT   OUT_RST_SZ
#define OUT_LORI   (OUT_RST_SZ + N_DST*LDIM)

// ---------------------------------------------------------------------------
// Kernel A: w_comb[j] = sum_i W_attn[j,i] * fW[i]  (j<256) ; block 256: c0
// ---------------------------------------------------------------------------
__global__ __launch_bounds__(256) void prep_kernel(
    const float* __restrict__ W_attn, const float* __restrict__ b_attn,
    const float* __restrict__ fW, float* __restrict__ ws) {
  __shared__ float red[256];
  int j = blockIdx.x;
  int t = threadIdx.x;
  const float* src = (j < ATTN_IN) ? &W_attn[(size_t)j * ATTN_OUT] : b_attn;
  float s = 0.f;
  for (int i = t; i < ATTN_OUT; i += 256) s += src[i] * fW[i];
  red[t] = s;
  __syncthreads();
  for (int stride = 128; stride > 0; stride >>= 1) {
    if (t < stride) red[t] += red[t + stride];
    __syncthreads();
  }
  if (t == 0) {
    if (j < ATTN_IN) ws[WS_WCOMB + j] = red[0];
    else             ws[WS_C0] = red[0];
  }
}

// ---------------------------------------------------------------------------
// Kernel B/D: C[M,128] = A[M,256] @ B[256,128] + bias
// Block tile 64x128, threads 256, per-thread 8x4 micro-tile.
// ---------------------------------------------------------------------------
__global__ __launch_bounds__(256) void gemm_k256_n128(
    const float* __restrict__ A, const float* __restrict__ B,
    const float* __restrict__ bias, float* __restrict__ C, int M) {
  __shared__ float As[64][64];    // [m][k] (row-major chunk of A)
  __shared__ float Bs[64][128];   // [k][n]
  const int t = threadIdx.x;
  const int m0 = blockIdx.x * 64;
  const int tm = (t >> 5) << 3;   // (t/32)*8 : 0..56
  const int tn = (t & 31) << 2;   // (t%32)*4 : 0..124
  float acc[8][4] = {};

  for (int k0 = 0; k0 < IN_F; k0 += 64) {
#pragma unroll
    for (int i = 0; i < 4; ++i) {
      int f = t + i * 256;        // 0..1023
      int row = f >> 4;           // 0..63
      int c4 = (f & 15) << 2;     // 0..60
      int gr = m0 + row;
      float4 av = make_float4(0.f, 0.f, 0.f, 0.f);
      if (gr < M) av = *(const float4*)&A[(size_t)gr * IN_F + k0 + c4];
      *(float4*)&As[row][c4] = av;
    }
#pragma unroll
    for (int i = 0; i < 8; ++i) {
      int f = t + i * 256;        // 0..2047
      int row = f >> 5;           // 0..63
      int c4 = (f & 31) << 2;     // 0..124
      *(float4*)&Bs[row][c4] = *(const float4*)&B[(size_t)(k0 + row) * OUT_F + c4];
    }
    __syncthreads();
#pragma unroll
    for (int kk = 0; kk < 64; ++kk) {
      float4 bv = *(const float4*)&Bs[kk][tn];
      float b[4] = {bv.x, bv.y, bv.z, bv.w};
#pragma unroll
      for (int i = 0; i < 8; ++i) {
        float a = As[tm + i][kk];
#pragma unroll
        for (int j = 0; j < 4; ++j) acc[i][j] += a * b[j];
      }
    }
    __syncthreads();
  }
  float4 bb = *(const float4*)&bias[tn];
#pragma unroll
  for (int i = 0; i < 8; ++i) {
    int gr = m0 + tm + i;
    if (gr < M) {
      float4 o;
      o.x = acc[i][0] + bb.x;
      o.y = acc[i][1] + bb.y;
      o.z = acc[i][2] + bb.z;
      o.w = acc[i][3] + bb.w;
      *(float4*)&C[(size_t)gr * OUT_F + tn] = o;
    }
  }
}

// ---------------------------------------------------------------------------
// Kernel C: per-dst fused attention + epilogue + label copies.
// Block = 256 threads (4 waves), one block per dst node.
// ---------------------------------------------------------------------------
__global__ __launch_bounds__(256) void attn_kernel(
    const float* __restrict__ labels, const float* __restrict__ labels_ori,
    const float* __restrict__ label_rela, const int* __restrict__ nbr_idx,
    const float* __restrict__ h_src, const float* __restrict__ self0,
    const float* __restrict__ w_comb, const float* __restrict__ c0p,
    const float* __restrict__ eps_p, const float* __restrict__ out_bias,
    float* __restrict__ out) {
  const int n = blockIdx.x;
  const int t = threadIdx.x;
  const int lane = t & 63;
  const int wave = t >> 6;

  __shared__ float hs[KNBR][OUT_F];   // raw gathered h rows (16 KB)
  __shared__ float v[16];
  __shared__ int   idx_s[KNBR];
  __shared__ float merge_s[KNBR];
  __shared__ float att_s[KNBR];
  __shared__ float cent_base_s;
  __shared__ float red[128];

  const float eps = eps_p[0];

  if (t < KNBR) idx_s[t] = nbr_idx[(size_t)n * KNBR + t];
  if (t < LDIM) {
    float s = 0.f;
#pragma unroll
    for (int b = 0; b < LDIM; ++b) s += label_rela[t * LDIM + b] * labels[(size_t)n * LDIM + b];
    v[t] = s;
  }
  // cent dot: threads 0..127 (waves 0,1)
  if (t < OUT_F) {
    float p = h_src[(size_t)n * OUT_F + t] * w_comb[OUT_F + t];
    for (int off = 32; off > 0; off >>= 1) p += __shfl_down(p, off);
    if (lane == 0) red[wave] = p;
  }
  __syncthreads();
  if (t == 0) cent_base_s = red[0] + red[1] + c0p[0];
  __syncthreads();

  // merge phase: wave w handles neighbors w*8 .. w*8+7
  const float wc0 = w_comb[2 * lane];
  const float wc1 = w_comb[2 * lane + 1];
  const float cent_base = cent_base_s;
#pragma unroll
  for (int kk = 0; kk < 8; ++kk) {
    int k = wave * 8 + kk;
    int idx = idx_s[k];
    float2 hv = *(const float2*)&h_src[(size_t)idx * OUT_F + 2 * lane];
    hs[k][2 * lane]     = hv.x;     // stage raw h for the PV step
    hs[k][2 * lane + 1] = hv.y;
    float ax = hv.x > 0.f ? hv.x : 0.1f * hv.x;
    float ay = hv.y > 0.f ? hv.y : 0.1f * hv.y;
    float p = ax * wc0 + ay * wc1;
    float q = (lane < LDIM) ? labels[(size_t)idx * LDIM + lane] * v[lane] : 0.f;
    for (int off = 32; off > 0; off >>= 1) p += __shfl_down(p, off);
    for (int off = 8; off > 0; off >>= 1) q += __shfl_down(q, off);
    if (lane == 0) {
      float fsim = p + cent_base;
      merge_s[k] = q * eps + fsim * (1.f - eps);
    }
  }
  __syncthreads();

  // softmax over 32 (wave 0)
  if (wave == 0) {
    float mv = (lane < KNBR) ? merge_s[lane] : -3.4e38f;
    for (int off = 32; off > 0; off >>= 1) {
      float o = __shfl_down(mv, off);
      mv = mv > o ? mv : o;
    }
    mv = __shfl(mv, 0);
    float e = (lane < KNBR) ? __expf(merge_s[lane] - mv) : 0.f;
    float s = e;
    for (int off = 32; off > 0; off >>= 1) s += __shfl_down(s, off);
    s = __shfl(s, 0);
    if (lane < KNBR) att_s[lane] = e / s;
  }
  __syncthreads();

  // weighted mean: 2 threads per output dim, 16 neighbors each
  const int d = t & 127;
  const int half = t >> 7;
  float acc = 0.f;
#pragma unroll
  for (int kk = 0; kk < 16; ++kk) {
    int k = half * 16 + kk;
    acc += att_s[k] * hs[k][d];
  }
  if (half == 1) red[d] = acc;
  __syncthreads();
  if (half == 0) {
    float neigh = (acc + red[d]) * (1.f / (float)KNBR);
    out[(size_t)n * OUT_F + d] =
        (self0[(size_t)n * OUT_F + d] + neigh) * 0.5f + out_bias[d];
  }
  if (t < LDIM) {
    out[OUT_CENT + (size_t)n * LDIM + t] = labels[(size_t)n * LDIM + t];
    out[OUT_LORI + (size_t)n * LDIM + t] = labels_ori[(size_t)n * LDIM + t];
  }
}

// ---------------------------------------------------------------------------
extern "C" void kernel_launch(void* const* d_in, const int* in_sizes, int n_in,
                              void* d_out, int out_size, void* d_ws, size_t ws_size,
                              hipStream_t stream) {
  const float* feat       = (const float*)d_in[0];
  const float* labels     = (const float*)d_in[1];
  const float* labels_ori = (const float*)d_in[2];
  const float* label_rela = (const float*)d_in[3];
  const float* W_neigh    = (const float*)d_in[4];
  const float* b_neigh    = (const float*)d_in[5];
  const float* W_self     = (const float*)d_in[6];
  const float* b_self     = (const float*)d_in[7];
  const float* W_attn     = (const float*)d_in[8];
  const float* b_attn     = (const float*)d_in[9];
  const float* fW         = (const float*)d_in[10];
  const float* eps        = (const float*)d_in[11];
  const float* out_bias   = (const float*)d_in[12];
  const int*   nbr_idx    = (const int*)d_in[13];

  float* ws  = (float*)d_ws;
  float* out = (float*)d_out;

  float* w_comb = ws + WS_WCOMB;
  float* c0     = ws + WS_C0;
  float* h_src  = ws + WS_HSRC;
  float* self0  = ws + WS_SELF0;

  // A: attention weight collapse
  prep_kernel<<<ATTN_IN + 1, 256, 0, stream>>>(W_attn, b_attn, fW, ws);

  // B: h_src = feat @ W_neigh + b_neigh  (50000 x 128)
  gemm_k256_n128<<<(N_SRC + 63) / 64, 256, 0, stream>>>(feat, W_neigh, b_neigh, h_src, N_SRC);

  // D: self0 = feat[:N_DST] @ W_self + b_self
  gemm_k256_n128<<<(N_DST + 63) / 64, 256, 0, stream>>>(feat, W_self, b_self, self0, N_DST);

  // C: fused attention + epilogue
  attn_kernel<<<N_DST, 256, 0, stream>>>(labels, labels_ori, label_rela, nbr_idx,
                                         h_src, self0, w_comb, c0, eps, out_bias, out);
}

// Round 2
// 78.249 us; speedup vs baseline: 1.9261x; 1.9261x over previous
//
#include <hip/hip_runtime.h>
#include <hip/hip_bf16.h>

#define N_SRC 50000
#define N_DST 10000
#define KNBR  32
#define IN_F  256
#define OUT_F 128
#define LDIM  10
#define ATTN_OUT 1024

using f32x4 = __attribute__((ext_vector_type(4))) float;
using s16x8 = __attribute__((ext_vector_type(8))) short;

// Output layout (floats): rst (N_DST*128) | cent_l (N_DST*10) | labels_ori[:N_DST] (N_DST*10)
#define OUT_CENT (N_DST*OUT_F)
#define OUT_LORI (N_DST*OUT_F + N_DST*LDIM)

// Workspace float offsets
#define WS_WCOMB 0                                   // 128 floats
#define WS_BN    128                                 // 32768 ushort = 16384 floats
#define WS_BS    (128 + 16384)                       // 32768 ushort
#define WS_HSRC  (128 + 32768)                       // N_SRC*128 ushort = 3.2M floats
#define WS_SELF0 (128 + 32768 + (N_SRC*OUT_F/2))     // N_DST*128 floats

__device__ __forceinline__ ushort f2bf(float x) {
  __hip_bfloat16 h = __float2bfloat16(x);
  return *reinterpret_cast<ushort*>(&h);
}

// ---------------------------------------------------------------------------
// prep: blocks 0..127   -> w_comb[j] = sum_i W_attn[j,i]*fW[i]  (only h_act part)
//       blocks 128..255 -> W_neigh fp32 -> bf16 subtiled [k/8][n][k&7]
//       blocks 256..383 -> W_self  same
// ---------------------------------------------------------------------------
__global__ __launch_bounds__(256) void prep_kernel(
    const float* __restrict__ W_attn, const float* __restrict__ fW,
    const float* __restrict__ W_neigh, const float* __restrict__ W_self,
    float* __restrict__ w_comb, ushort* __restrict__ Bn, ushort* __restrict__ Bs) {
  const int b = blockIdx.x;
  const int t = threadIdx.x;
  if (b < 128) {
    __shared__ float red[256];
    float s = 0.f;
#pragma unroll
    for (int i = 0; i < 4; ++i) {
      int o = t + i * 256;
      s += W_attn[(size_t)b * ATTN_OUT + o] * fW[o];
    }
    red[t] = s;
    __syncthreads();
    for (int st = 128; st > 0; st >>= 1) {
      if (t < st) red[t] += red[t + st];
      __syncthreads();
    }
    if (t == 0) w_comb[b] = red[0];
  } else if (b < 256) {
    int k = 2 * (b - 128) + (t >> 7);
    int n = t & 127;
    float x = W_neigh[(size_t)k * OUT_F + n];
    Bn[(k >> 3) * 1024 + n * 8 + (k & 7)] = f2bf(x);
  } else {
    int k = 2 * (b - 256) + (t >> 7);
    int n = t & 127;
    float x = W_self[(size_t)k * OUT_F + n];
    Bs[(k >> 3) * 1024 + n * 8 + (k & 7)] = f2bf(x);
  }
}

// ---------------------------------------------------------------------------
// MFMA GEMM: C[M,128] = A[M,256] @ B + bias.  B pre-converted bf16, subtiled
// [32][128][8] so fragment reads are contiguous ds_read_b128, loaded whole
// into LDS once (no K-loop barriers).  Block: 256 thr / 4 waves; tile 128x128;
// wave = 32 rows.  A streamed global->reg->bf16.
// ---------------------------------------------------------------------------
template<bool OUT_BF16>
__global__ __launch_bounds__(256) void mfma_gemm(
    const float* __restrict__ A, const ushort* __restrict__ Bp,
    const float* __restrict__ bias, void* __restrict__ C, int M) {
  __shared__ ushort Bsh[32768];   // 64 KB
  const int t = threadIdx.x;
  {
    const uint4* g = (const uint4*)Bp;
    uint4* l = (uint4*)Bsh;
#pragma unroll
    for (int it = 0; it < 16; ++it) l[t + it * 256] = g[t + it * 256];
  }
  __syncthreads();

  const int wv = t >> 6, ln = t & 63;
  const int kg = ln >> 4;                       // 0..3
  const int m0 = blockIdx.x * 128;
  const int rbase = m0 + wv * 32 + (ln & 15);   // A-fragment row

  f32x4 acc[2][8];
#pragma unroll
  for (int rt = 0; rt < 2; ++rt)
#pragma unroll
    for (int ct = 0; ct < 8; ++ct) acc[rt][ct] = (f32x4){0.f, 0.f, 0.f, 0.f};

#pragma unroll
  for (int k0 = 0; k0 < IN_F; k0 += 32) {
    s16x8 afr[2];
#pragma unroll
    for (int rt = 0; rt < 2; ++rt) {
      int r = rbase + rt * 16;
      f32x4 a0 = {0.f, 0.f, 0.f, 0.f}, a1 = {0.f, 0.f, 0.f, 0.f};
      if (r < M) {
        const f32x4* ap = (const f32x4*)&A[(size_t)r * IN_F + k0 + kg * 8];
        a0 = ap[0];
        a1 = ap[1];
      }
      s16x8 f;
      f[0] = (short)f2bf(a0[0]); f[1] = (short)f2bf(a0[1]);
      f[2] = (short)f2bf(a0[2]); f[3] = (short)f2bf(a0[3]);
      f[4] = (short)f2bf(a1[0]); f[5] = (short)f2bf(a1[1]);
      f[6] = (short)f2bf(a1[2]); f[7] = (short)f2bf(a1[3]);
      afr[rt] = f;
    }
    const int sbase = ((k0 >> 3) + kg) * 1024 + (ln & 15) * 8;
#pragma unroll
    for (int ct = 0; ct < 8; ++ct) {
      s16x8 bfr = *reinterpret_cast<const s16x8*>(&Bsh[sbase + ct * 128]);
      acc[0][ct] = __builtin_amdgcn_mfma_f32_16x16x32_bf16(afr[0], bfr, acc[0][ct], 0, 0, 0);
      acc[1][ct] = __builtin_amdgcn_mfma_f32_16x16x32_bf16(afr[1], bfr, acc[1][ct], 0, 0, 0);
    }
  }
  // Epilogue. D layout: col = ln&15, row = 4*kg + e (HW-verified m89).
#pragma unroll
  for (int ct = 0; ct < 8; ++ct) {
    int col = ct * 16 + (ln & 15);
    float bb = bias[col];
#pragma unroll
    for (int rt = 0; rt < 2; ++rt) {
#pragma unroll
      for (int e = 0; e < 4; ++e) {
        int r = m0 + wv * 32 + rt * 16 + kg * 4 + e;
        if (r < M) {
          float v = acc[rt][ct][e] + bb;
          if (OUT_BF16) ((ushort*)C)[(size_t)r * OUT_F + col] = f2bf(v);
          else          ((float*)C)[(size_t)r * OUT_F + col] = v;
        }
      }
    }
  }
}

// ---------------------------------------------------------------------------
// attn: one wave per dst node.  Lane (dg = l&15, kg = l>>4): dims dg*8..+8,
// neighbors kg*8..+8.  Softmax shift-invariance drops the whole cent/c0/b_attn
// constant.  merge partial per lane = (1-eps)*sum_e wc*leaky(h) + eps*lbl*v.
// ---------------------------------------------------------------------------
__global__ __launch_bounds__(256) void attn_kernel(
    const float* __restrict__ labels, const float* __restrict__ labels_ori,
    const float* __restrict__ label_rela, const int* __restrict__ nbr_idx,
    const ushort* __restrict__ hsrc, const float* __restrict__ self0,
    const float* __restrict__ w_comb, const float* __restrict__ eps_p,
    const float* __restrict__ out_bias, float* __restrict__ out) {
  const int t = threadIdx.x;
  const int wv = t >> 6, ln = t & 63;
  const int n = blockIdx.x * 4 + wv;
  const int dg = ln & 15, kg = ln >> 4;

  const float eps = eps_p[0];
  const float om = 1.f - eps;

  // premultiplied attention weights for this lane's 8 dims
  float wcs[8];
  {
    const f32x4* wp = (const f32x4*)&w_comb[dg * 8];
    f32x4 w0 = wp[0], w1 = wp[1];
    wcs[0] = om * w0[0]; wcs[1] = om * w0[1]; wcs[2] = om * w0[2]; wcs[3] = om * w0[3];
    wcs[4] = om * w1[0]; wcs[5] = om * w1[1]; wcs[6] = om * w1[2]; wcs[7] = om * w1[3];
  }
  // v[dg] = sum_b rela[dg][b]*cent_l[b], folded with eps
  float va = 0.f;
  if (dg < LDIM) {
#pragma unroll
    for (int b = 0; b < LDIM; ++b)
      va += label_rela[dg * LDIM + b] * labels[(size_t)n * LDIM + b];
    va *= eps;
  }

  const int* irow = nbr_idx + (size_t)n * KNBR;
  float hf[8][8];
  float m[8];
#pragma unroll
  for (int j = 0; j < 8; ++j) {
    int id = irow[kg * 8 + j];
    uint4 hv = *(const uint4*)(hsrc + (size_t)id * OUT_F + dg * 8);
    hf[j][0] = __uint_as_float(hv.x << 16);
    hf[j][1] = __uint_as_float(hv.x & 0xffff0000u);
    hf[j][2] = __uint_as_float(hv.y << 16);
    hf[j][3] = __uint_as_float(hv.y & 0xffff0000u);
    hf[j][4] = __uint_as_float(hv.z << 16);
    hf[j][5] = __uint_as_float(hv.z & 0xffff0000u);
    hf[j][6] = __uint_as_float(hv.w << 16);
    hf[j][7] = __uint_as_float(hv.w & 0xffff0000u);
    float p = 0.f;
#pragma unroll
    for (int e = 0; e < 8; ++e)
      p = fmaf(fmaxf(hf[j][e], 0.1f * hf[j][e]), wcs[e], p);
    if (dg < LDIM) p = fmaf(labels[(size_t)id * LDIM + dg], va, p);
    m[j] = p;
  }
  // reduce merge partials across the 16 dim-lanes
#pragma unroll
  for (int s = 1; s < 16; s <<= 1) {
#pragma unroll
    for (int j = 0; j < 8; ++j) m[j] += __shfl_xor(m[j], s);
  }
  // softmax over all 32 neighbors
  float mx = m[0];
#pragma unroll
  for (int j = 1; j < 8; ++j) mx = fmaxf(mx, m[j]);
  mx = fmaxf(mx, __shfl_xor(mx, 16));
  mx = fmaxf(mx, __shfl_xor(mx, 32));
  float ssum = 0.f;
#pragma unroll
  for (int j = 0; j < 8; ++j) {
    m[j] = __expf(m[j] - mx);
    ssum += m[j];
  }
  ssum += __shfl_xor(ssum, 16);
  ssum += __shfl_xor(ssum, 32);
  const float scale = 1.f / (ssum * (float)KNBR);
  // PV: per-lane partial over this kg's 8 neighbors, then fold kg groups
  float pn[8];
#pragma unroll
  for (int e = 0; e < 8; ++e) pn[e] = 0.f;
#pragma unroll
  for (int j = 0; j < 8; ++j) {
#pragma unroll
    for (int e = 0; e < 8; ++e) pn[e] = fmaf(m[j], hf[j][e], pn[e]);
  }
#pragma unroll
  for (int e = 0; e < 8; ++e) {
    pn[e] += __shfl_xor(pn[e], 16);
    pn[e] += __shfl_xor(pn[e], 32);
  }
  // epilogue
  if (kg == 0) {
    const float* srow = self0 + (size_t)n * OUT_F + dg * 8;
    float* orow = out + (size_t)n * OUT_F + dg * 8;
    f32x4 o0, o1;
#pragma unroll
    for (int e = 0; e < 4; ++e)
      o0[e] = (srow[e] + pn[e] * scale) * 0.5f + out_bias[dg * 8 + e];
#pragma unroll
    for (int e = 0; e < 4; ++e)
      o1[e] = (srow[4 + e] + pn[4 + e] * scale) * 0.5f + out_bias[dg * 8 + 4 + e];
    *(f32x4*)orow = o0;
    *(f32x4*)(orow + 4) = o1;
  }
  if (kg == 1 && dg < LDIM)
    out[OUT_CENT + (size_t)n * LDIM + dg] = labels[(size_t)n * LDIM + dg];
  if (kg == 2 && dg < LDIM)
    out[OUT_LORI + (size_t)n * LDIM + dg] = labels_ori[(size_t)n * LDIM + dg];
}

// ---------------------------------------------------------------------------
extern "C" void kernel_launch(void* const* d_in, const int* in_sizes, int n_in,
                              void* d_out, int out_size, void* d_ws, size_t ws_size,
                              hipStream_t stream) {
  const float* feat       = (const float*)d_in[0];
  const float* labels     = (const float*)d_in[1];
  const float* labels_ori = (const float*)d_in[2];
  const float* label_rela = (const float*)d_in[3];
  const float* W_neigh    = (const float*)d_in[4];
  const float* b_neigh    = (const float*)d_in[5];
  const float* W_self     = (const float*)d_in[6];
  const float* b_self     = (const float*)d_in[7];
  const float* W_attn     = (const float*)d_in[8];
  // d_in[9] = b_attn (constant under softmax -> unused)
  const float* fW         = (const float*)d_in[10];
  const float* eps        = (const float*)d_in[11];
  const float* out_bias   = (const float*)d_in[12];
  const int*   nbr_idx    = (const int*)d_in[13];

  float* wsf = (float*)d_ws;
  float* out = (float*)d_out;

  float*  w_comb = wsf + WS_WCOMB;
  ushort* Bn     = (ushort*)(wsf + WS_BN);
  ushort* Bsf    = (ushort*)(wsf + WS_BS);
  ushort* h_src  = (ushort*)(wsf + WS_HSRC);
  float*  self0  = wsf + WS_SELF0;

  prep_kernel<<<384, 256, 0, stream>>>(W_attn, fW, W_neigh, W_self, w_comb, Bn, Bsf);
  mfma_gemm<true><<<(N_SRC + 127) / 128, 256, 0, stream>>>(feat, Bn, b_neigh, (void*)h_src, N_SRC);
  mfma_gemm<false><<<(N_DST + 127) / 128, 256, 0, stream>>>(feat, Bsf, b_self, (void*)self0, N_DST);
  attn_kernel<<<(N_DST / 4), 256, 0, stream>>>(labels, labels_ori, label_rela, nbr_idx,
                                               h_src, self0, w_comb, eps, out_bias, out);
}

// Round 3
// 76.865 us; speedup vs baseline: 1.9608x; 1.0180x over previous
//
#include <hip/hip_runtime.h>
#include <hip/hip_bf16.h>

#define N_SRC 50000
#define N_DST 10000
#define KNBR  32
#define IN_F  256
#define OUT_F 128
#define LDIM  10
#define ATTN_OUT 1024
#define NB_BIG  391   // ceil(50000/128)
#define NB_SELF 79    // ceil(10000/128)

using f32x4 = __attribute__((ext_vector_type(4))) float;
using s16x8 = __attribute__((ext_vector_type(8))) short;

// Output layout (floats): rst (N_DST*128) | cent_l (N_DST*10) | labels_ori[:N_DST] (N_DST*10)
#define OUT_CENT (N_DST*OUT_F)
#define OUT_LORI (N_DST*OUT_F + N_DST*LDIM)

// Workspace float offsets
#define WS_WCOMB 0                                   // 128 floats
#define WS_BN    128                                 // 32768 ushort = 16384 floats
#define WS_BS    (128 + 16384)                       // 32768 ushort
#define WS_HSRC  (128 + 32768)                       // N_SRC*128 ushort = 3.2M floats
#define WS_SELF0 (128 + 32768 + (N_SRC*OUT_F/2))     // N_DST*128 floats

__device__ __forceinline__ ushort f2bf(float x) {
  __hip_bfloat16 h = __float2bfloat16(x);
  return *reinterpret_cast<ushort*>(&h);
}

// ---------------------------------------------------------------------------
// prep: blocks 0..127   -> w_comb[j] = sum_i W_attn[j,i]*fW[i]  (h_act part)
//       blocks 128..255 -> W_neigh fp32 -> bf16 subtiled [k/8][n][k&7]
//       blocks 256..383 -> W_self  same
// ---------------------------------------------------------------------------
__global__ __launch_bounds__(256) void prep_kernel(
    const float* __restrict__ W_attn, const float* __restrict__ fW,
    const float* __restrict__ W_neigh, const float* __restrict__ W_self,
    float* __restrict__ w_comb, ushort* __restrict__ Bn, ushort* __restrict__ Bs) {
  const int b = blockIdx.x;
  const int t = threadIdx.x;
  if (b < 128) {
    __shared__ float red[256];
    float s = 0.f;
#pragma unroll
    for (int i = 0; i < 4; ++i) {
      int o = t + i * 256;
      s += W_attn[(size_t)b * ATTN_OUT + o] * fW[o];
    }
    red[t] = s;
    __syncthreads();
    for (int st = 128; st > 0; st >>= 1) {
      if (t < st) red[t] += red[t + st];
      __syncthreads();
    }
    if (t == 0) w_comb[b] = red[0];
  } else if (b < 256) {
    int k = 2 * (b - 128) + (t >> 7);
    int n = t & 127;
    float x = W_neigh[(size_t)k * OUT_F + n];
    Bn[(k >> 3) * 1024 + n * 8 + (k & 7)] = f2bf(x);
  } else {
    int k = 2 * (b - 256) + (t >> 7);
    int n = t & 127;
    float x = W_self[(size_t)k * OUT_F + n];
    Bs[(k >> 3) * 1024 + n * 8 + (k & 7)] = f2bf(x);
  }
}

// ---------------------------------------------------------------------------
// MFMA GEMM body, no LDS: B fragments streamed from the 64 KB pre-subtiled
// bf16 table (L1/L2-resident; staging it in LDS costs more than it saves —
// guide common-mistake #7). No barriers anywhere: compiler pipelines the
// fully-unrolled K-loop. Block 256 thr / 4 waves; tile 128x128; wave = 32
// rows (2 row-tiles, B-frag reused 2x).  A: global fp32 -> reg -> bf16.
// ---------------------------------------------------------------------------
template<bool OUT_BF16>
__device__ __forceinline__ void gemm_body(
    const float* __restrict__ A, const ushort* __restrict__ Bp,
    const float* __restrict__ bias, void* __restrict__ C, int M, int m0) {
  const int t = threadIdx.x;
  const int wv = t >> 6, ln = t & 63;
  const int dg = ln & 15, kg = ln >> 4;
  const int rbase = m0 + wv * 32 + dg;

  f32x4 acc[2][8];
#pragma unroll
  for (int rt = 0; rt < 2; ++rt)
#pragma unroll
    for (int ct = 0; ct < 8; ++ct) acc[rt][ct] = (f32x4){0.f, 0.f, 0.f, 0.f};

#pragma unroll
  for (int k0 = 0; k0 < IN_F; k0 += 32) {
    s16x8 afr[2];
#pragma unroll
    for (int rt = 0; rt < 2; ++rt) {
      int r = rbase + rt * 16;
      r = r < M ? r : M - 1;                 // branchless clamp: load always valid
      const f32x4* ap = (const f32x4*)&A[(size_t)r * IN_F + k0 + kg * 8];
      f32x4 a0 = ap[0];
      f32x4 a1 = ap[1];
      s16x8 f;
      f[0] = (short)f2bf(a0[0]); f[1] = (short)f2bf(a0[1]);
      f[2] = (short)f2bf(a0[2]); f[3] = (short)f2bf(a0[3]);
      f[4] = (short)f2bf(a1[0]); f[5] = (short)f2bf(a1[1]);
      f[6] = (short)f2bf(a1[2]); f[7] = (short)f2bf(a1[3]);
      afr[rt] = f;
    }
    const ushort* bb = Bp + ((k0 >> 3) + kg) * 1024 + dg * 8;
#pragma unroll
    for (int ct = 0; ct < 8; ++ct) {
      s16x8 bfr = *reinterpret_cast<const s16x8*>(bb + ct * 128);
      acc[0][ct] = __builtin_amdgcn_mfma_f32_16x16x32_bf16(afr[0], bfr, acc[0][ct], 0, 0, 0);
      acc[1][ct] = __builtin_amdgcn_mfma_f32_16x16x32_bf16(afr[1], bfr, acc[1][ct], 0, 0, 0);
    }
  }
  // Epilogue. D layout: col = ln&15, row = 4*kg + e (HW-verified m89).
#pragma unroll
  for (int ct = 0; ct < 8; ++ct) {
    int col = ct * 16 + dg;
    float bb = bias[col];
#pragma unroll
    for (int rt = 0; rt < 2; ++rt) {
#pragma unroll
      for (int e = 0; e < 4; ++e) {
        int r = m0 + wv * 32 + rt * 16 + kg * 4 + e;
        if (r < M) {
          float v = acc[rt][ct][e] + bb;
          if (OUT_BF16) ((ushort*)C)[(size_t)r * OUT_F + col] = f2bf(v);
          else          ((float*)C)[(size_t)r * OUT_F + col] = v;
        }
      }
    }
  }
}

__global__ __launch_bounds__(256) void fused_gemm(
    const float* __restrict__ A,
    const ushort* __restrict__ Bn, const ushort* __restrict__ Bs,
    const float* __restrict__ bias_n, const float* __restrict__ bias_s,
    ushort* __restrict__ hsrc, float* __restrict__ self0) {
  if (blockIdx.x < NB_BIG)
    gemm_body<true>(A, Bn, bias_n, (void*)hsrc, N_SRC, blockIdx.x * 128);
  else
    gemm_body<false>(A, Bs, bias_s, (void*)self0, N_DST, (blockIdx.x - NB_BIG) * 128);
}

// ---------------------------------------------------------------------------
// attn: one wave per dst node (UNCHANGED from round 2 for delta attribution).
// ---------------------------------------------------------------------------
__global__ __launch_bounds__(256) void attn_kernel(
    const float* __restrict__ labels, const float* __restrict__ labels_ori,
    const float* __restrict__ label_rela, const int* __restrict__ nbr_idx,
    const ushort* __restrict__ hsrc, const float* __restrict__ self0,
    const float* __restrict__ w_comb, const float* __restrict__ eps_p,
    const float* __restrict__ out_bias, float* __restrict__ out) {
  const int t = threadIdx.x;
  const int wv = t >> 6, ln = t & 63;
  const int n = blockIdx.x * 4 + wv;
  const int dg = ln & 15, kg = ln >> 4;

  const float eps = eps_p[0];
  const float om = 1.f - eps;

  float wcs[8];
  {
    const f32x4* wp = (const f32x4*)&w_comb[dg * 8];
    f32x4 w0 = wp[0], w1 = wp[1];
    wcs[0] = om * w0[0]; wcs[1] = om * w0[1]; wcs[2] = om * w0[2]; wcs[3] = om * w0[3];
    wcs[4] = om * w1[0]; wcs[5] = om * w1[1]; wcs[6] = om * w1[2]; wcs[7] = om * w1[3];
  }
  float va = 0.f;
  if (dg < LDIM) {
#pragma unroll
    for (int b = 0; b < LDIM; ++b)
      va += label_rela[dg * LDIM + b] * labels[(size_t)n * LDIM + b];
    va *= eps;
  }

  const int* irow = nbr_idx + (size_t)n * KNBR;
  float hf[8][8];
  float m[8];
#pragma unroll
  for (int j = 0; j < 8; ++j) {
    int id = irow[kg * 8 + j];
    uint4 hv = *(const uint4*)(hsrc + (size_t)id * OUT_F + dg * 8);
    hf[j][0] = __uint_as_float(hv.x << 16);
    hf[j][1] = __uint_as_float(hv.x & 0xffff0000u);
    hf[j][2] = __uint_as_float(hv.y << 16);
    hf[j][3] = __uint_as_float(hv.y & 0xffff0000u);
    hf[j][4] = __uint_as_float(hv.z << 16);
    hf[j][5] = __uint_as_float(hv.z & 0xffff0000u);
    hf[j][6] = __uint_as_float(hv.w << 16);
    hf[j][7] = __uint_as_float(hv.w & 0xffff0000u);
    float p = 0.f;
#pragma unroll
    for (int e = 0; e < 8; ++e)
      p = fmaf(fmaxf(hf[j][e], 0.1f * hf[j][e]), wcs[e], p);
    if (dg < LDIM) p = fmaf(labels[(size_t)id * LDIM + dg], va, p);
    m[j] = p;
  }
#pragma unroll
  for (int s = 1; s < 16; s <<= 1) {
#pragma unroll
    for (int j = 0; j < 8; ++j) m[j] += __shfl_xor(m[j], s);
  }
  float mx = m[0];
#pragma unroll
  for (int j = 1; j < 8; ++j) mx = fmaxf(mx, m[j]);
  mx = fmaxf(mx, __shfl_xor(mx, 16));
  mx = fmaxf(mx, __shfl_xor(mx, 32));
  float ssum = 0.f;
#pragma unroll
  for (int j = 0; j < 8; ++j) {
    m[j] = __expf(m[j] - mx);
    ssum += m[j];
  }
  ssum += __shfl_xor(ssum, 16);
  ssum += __shfl_xor(ssum, 32);
  const float scale = 1.f / (ssum * (float)KNBR);
  float pn[8];
#pragma unroll
  for (int e = 0; e < 8; ++e) pn[e] = 0.f;
#pragma unroll
  for (int j = 0; j < 8; ++j) {
#pragma unroll
    for (int e = 0; e < 8; ++e) pn[e] = fmaf(m[j], hf[j][e], pn[e]);
  }
#pragma unroll
  for (int e = 0; e < 8; ++e) {
    pn[e] += __shfl_xor(pn[e], 16);
    pn[e] += __shfl_xor(pn[e], 32);
  }
  if (kg == 0) {
    const float* srow = self0 + (size_t)n * OUT_F + dg * 8;
    float* orow = out + (size_t)n * OUT_F + dg * 8;
    f32x4 o0, o1;
#pragma unroll
    for (int e = 0; e < 4; ++e)
      o0[e] = (srow[e] + pn[e] * scale) * 0.5f + out_bias[dg * 8 + e];
#pragma unroll
    for (int e = 0; e < 4; ++e)
      o1[e] = (srow[4 + e] + pn[4 + e] * scale) * 0.5f + out_bias[dg * 8 + 4 + e];
    *(f32x4*)orow = o0;
    *(f32x4*)(orow + 4) = o1;
  }
  if (kg == 1 && dg < LDIM)
    out[OUT_CENT + (size_t)n * LDIM + dg] = labels[(size_t)n * LDIM + dg];
  if (kg == 2 && dg < LDIM)
    out[OUT_LORI + (size_t)n * LDIM + dg] = labels_ori[(size_t)n * LDIM + dg];
}

// ---------------------------------------------------------------------------
extern "C" void kernel_launch(void* const* d_in, const int* in_sizes, int n_in,
                              void* d_out, int out_size, void* d_ws, size_t ws_size,
                              hipStream_t stream) {
  const float* feat       = (const float*)d_in[0];
  const float* labels     = (const float*)d_in[1];
  const float* labels_ori = (const float*)d_in[2];
  const float* label_rela = (const float*)d_in[3];
  const float* W_neigh    = (const float*)d_in[4];
  const float* b_neigh    = (const float*)d_in[5];
  const float* W_self     = (const float*)d_in[6];
  const float* b_self     = (const float*)d_in[7];
  const float* W_attn     = (const float*)d_in[8];
  // d_in[9] = b_attn (constant under softmax -> unused)
  const float* fW         = (const float*)d_in[10];
  const float* eps        = (const float*)d_in[11];
  const float* out_bias   = (const float*)d_in[12];
  const int*   nbr_idx    = (const int*)d_in[13];

  float* wsf = (float*)d_ws;
  float* out = (float*)d_out;

  float*  w_comb = wsf + WS_WCOMB;
  ushort* Bn     = (ushort*)(wsf + WS_BN);
  ushort* Bsf    = (ushort*)(wsf + WS_BS);
  ushort* h_src  = (ushort*)(wsf + WS_HSRC);
  float*  self0  = wsf + WS_SELF0;

  prep_kernel<<<384, 256, 0, stream>>>(W_attn, fW, W_neigh, W_self, w_comb, Bn, Bsf);
  fused_gemm<<<NB_BIG + NB_SELF, 256, 0, stream>>>(feat, Bn, Bsf, b_neigh, b_self, h_src, self0);
  attn_kernel<<<(N_DST / 4), 256, 0, stream>>>(labels, labels_ori, label_rela, nbr_idx,
                                               h_src, self0, w_comb, eps, out_bias, out);
}

// Round 4
// 65.754 us; speedup vs baseline: 2.2921x; 1.1690x over previous
//
#include <hip/hip_runtime.h>
#include <hip/hip_bf16.h>

#define N_SRC 50000
#define N_DST 10000
#define KNBR  32
#define IN_F  256
#define OUT_F 128
#define LDIM  10
#define ATTN_OUT 1024
#define NB_BIG  782   // ceil(50000/64)
#define NB_SELF 157   // ceil(10000/64)

using f32x4 = __attribute__((ext_vector_type(4))) float;
using s16x8 = __attribute__((ext_vector_type(8))) short;

// Output layout (floats): rst (N_DST*128) | cent_l (N_DST*10) | labels_ori[:N_DST] (N_DST*10)
#define OUT_CENT (N_DST*OUT_F)
#define OUT_LORI (N_DST*OUT_F + N_DST*LDIM)

// Workspace float offsets
#define WS_WCOMB 0                                   // 128 floats
#define WS_BN    128                                 // 32768 ushort = 16384 floats
#define WS_BS    (128 + 16384)                       // 32768 ushort
#define WS_HSRC  (128 + 32768)                       // N_SRC*128 ushort = 3.2M floats
#define WS_SELF0 (128 + 32768 + (N_SRC*OUT_F/2))     // N_DST*128 floats

__device__ __forceinline__ ushort f2bf(float x) {
  __hip_bfloat16 h = __float2bfloat16(x);
  return *reinterpret_cast<ushort*>(&h);
}

// ---------------------------------------------------------------------------
// prep: blocks 0..127   -> w_comb[j] = sum_i W_attn[j,i]*fW[i]  (h_act part)
//       blocks 128..255 -> W_neigh fp32 -> bf16 subtiled [k/8][n][k&7]
//       blocks 256..383 -> W_self  same
// ---------------------------------------------------------------------------
__global__ __launch_bounds__(256) void prep_kernel(
    const float* __restrict__ W_attn, const float* __restrict__ fW,
    const float* __restrict__ W_neigh, const float* __restrict__ W_self,
    float* __restrict__ w_comb, ushort* __restrict__ Bn, ushort* __restrict__ Bs) {
  const int b = blockIdx.x;
  const int t = threadIdx.x;
  if (b < 128) {
    __shared__ float red[256];
    float s = 0.f;
#pragma unroll
    for (int i = 0; i < 4; ++i) {
      int o = t + i * 256;
      s += W_attn[(size_t)b * ATTN_OUT + o] * fW[o];
    }
    red[t] = s;
    __syncthreads();
    for (int st = 128; st > 0; st >>= 1) {
      if (t < st) red[t] += red[t + st];
      __syncthreads();
    }
    if (t == 0) w_comb[b] = red[0];
  } else if (b < 256) {
    int k = 2 * (b - 128) + (t >> 7);
    int n = t & 127;
    float x = W_neigh[(size_t)k * OUT_F + n];
    Bn[(k >> 3) * 1024 + n * 8 + (k & 7)] = f2bf(x);
  } else {
    int k = 2 * (b - 256) + (t >> 7);
    int n = t & 127;
    float x = W_self[(size_t)k * OUT_F + n];
    Bs[(k >> 3) * 1024 + n * 8 + (k & 7)] = f2bf(x);
  }
}

// ---------------------------------------------------------------------------
// MFMA GEMM body, no LDS. Tile 64 rows/block, wave = 16 rows (acc[8] only ->
// low VGPR, more waves in flight). Phase 1: issue ALL 16 HBM A-loads for this
// lane's row at once (single latency exposure), cvt to bf16. Phase 2: 64 MFMAs
// fed by B-frag loads from the L2-resident pre-subtiled 64 KB table.
// ---------------------------------------------------------------------------
template<bool OUT_BF16>
__device__ __forceinline__ void gemm_body(
    const float* __restrict__ A, const ushort* __restrict__ Bp,
    const float* __restrict__ bias, void* __restrict__ C, int M, int m0) {
  const int t = threadIdx.x;
  const int wv = t >> 6, ln = t & 63;
  const int dg = ln & 15, kg = ln >> 4;
  int r = m0 + wv * 16 + dg;
  r = r < M ? r : M - 1;                    // branchless clamp: loads always valid

  // Phase 1: whole A row slice for this lane: k in {k0+kg*8 .. +8} for 8 k0s.
  f32x4 araw[16];
  const float* arow = &A[(size_t)r * IN_F];
#pragma unroll
  for (int k0 = 0; k0 < 8; ++k0) {
    const f32x4* ap = (const f32x4*)&arow[k0 * 32 + kg * 8];
    araw[2 * k0]     = ap[0];
    araw[2 * k0 + 1] = ap[1];
  }
  s16x8 afr[8];
#pragma unroll
  for (int k0 = 0; k0 < 8; ++k0) {
    s16x8 f;
    f[0] = (short)f2bf(araw[2*k0][0]); f[1] = (short)f2bf(araw[2*k0][1]);
    f[2] = (short)f2bf(araw[2*k0][2]); f[3] = (short)f2bf(araw[2*k0][3]);
    f[4] = (short)f2bf(araw[2*k0+1][0]); f[5] = (short)f2bf(araw[2*k0+1][1]);
    f[6] = (short)f2bf(araw[2*k0+1][2]); f[7] = (short)f2bf(araw[2*k0+1][3]);
    afr[k0] = f;
  }

  // Phase 2: MFMA chain, B-frags streamed from L2.
  f32x4 acc[8];
#pragma unroll
  for (int ct = 0; ct < 8; ++ct) acc[ct] = (f32x4){0.f, 0.f, 0.f, 0.f};
#pragma unroll
  for (int k0 = 0; k0 < 8; ++k0) {
    const ushort* bb = Bp + (k0 * 4 + kg) * 1024 + dg * 8;
#pragma unroll
    for (int ct = 0; ct < 8; ++ct) {
      s16x8 bfr = *reinterpret_cast<const s16x8*>(bb + ct * 128);
      acc[ct] = __builtin_amdgcn_mfma_f32_16x16x32_bf16(afr[k0], bfr, acc[ct], 0, 0, 0);
    }
  }

  // Epilogue. D layout: col = ln&15, row = 4*kg + e (HW-verified m89).
#pragma unroll
  for (int ct = 0; ct < 8; ++ct) {
    int col = ct * 16 + dg;
    float bb = bias[col];
#pragma unroll
    for (int e = 0; e < 4; ++e) {
      int rr = m0 + wv * 16 + kg * 4 + e;
      if (rr < M) {
        float v = acc[ct][e] + bb;
        if (OUT_BF16) ((ushort*)C)[(size_t)rr * OUT_F + col] = f2bf(v);
        else          ((float*)C)[(size_t)rr * OUT_F + col] = v;
      }
    }
  }
}

__global__ __launch_bounds__(256) void fused_gemm(
    const float* __restrict__ A,
    const ushort* __restrict__ Bn, const ushort* __restrict__ Bs,
    const float* __restrict__ bias_n, const float* __restrict__ bias_s,
    ushort* __restrict__ hsrc, float* __restrict__ self0) {
  if (blockIdx.x < NB_BIG)
    gemm_body<true>(A, Bn, bias_n, (void*)hsrc, N_SRC, blockIdx.x * 64);
  else
    gemm_body<false>(A, Bs, bias_s, (void*)self0, N_DST, (blockIdx.x - NB_BIG) * 64);
}

// ---------------------------------------------------------------------------
// attn: one wave per dst node (UNCHANGED for delta attribution).
// ---------------------------------------------------------------------------
__global__ __launch_bounds__(256) void attn_kernel(
    const float* __restrict__ labels, const float* __restrict__ labels_ori,
    const float* __restrict__ label_rela, const int* __restrict__ nbr_idx,
    const ushort* __restrict__ hsrc, const float* __restrict__ self0,
    const float* __restrict__ w_comb, const float* __restrict__ eps_p,
    const float* __restrict__ out_bias, float* __restrict__ out) {
  const int t = threadIdx.x;
  const int wv = t >> 6, ln = t & 63;
  const int n = blockIdx.x * 4 + wv;
  const int dg = ln & 15, kg = ln >> 4;

  const float eps = eps_p[0];
  const float om = 1.f - eps;

  float wcs[8];
  {
    const f32x4* wp = (const f32x4*)&w_comb[dg * 8];
    f32x4 w0 = wp[0], w1 = wp[1];
    wcs[0] = om * w0[0]; wcs[1] = om * w0[1]; wcs[2] = om * w0[2]; wcs[3] = om * w0[3];
    wcs[4] = om * w1[0]; wcs[5] = om * w1[1]; wcs[6] = om * w1[2]; wcs[7] = om * w1[3];
  }
  float va = 0.f;
  if (dg < LDIM) {
#pragma unroll
    for (int b = 0; b < LDIM; ++b)
      va += label_rela[dg * LDIM + b] * labels[(size_t)n * LDIM + b];
    va *= eps;
  }

  const int* irow = nbr_idx + (size_t)n * KNBR;
  float hf[8][8];
  float m[8];
#pragma unroll
  for (int j = 0; j < 8; ++j) {
    int id = irow[kg * 8 + j];
    uint4 hv = *(const uint4*)(hsrc + (size_t)id * OUT_F + dg * 8);
    hf[j][0] = __uint_as_float(hv.x << 16);
    hf[j][1] = __uint_as_float(hv.x & 0xffff0000u);
    hf[j][2] = __uint_as_float(hv.y << 16);
    hf[j][3] = __uint_as_float(hv.y & 0xffff0000u);
    hf[j][4] = __uint_as_float(hv.z << 16);
    hf[j][5] = __uint_as_float(hv.z & 0xffff0000u);
    hf[j][6] = __uint_as_float(hv.w << 16);
    hf[j][7] = __uint_as_float(hv.w & 0xffff0000u);
    float p = 0.f;
#pragma unroll
    for (int e = 0; e < 8; ++e)
      p = fmaf(fmaxf(hf[j][e], 0.1f * hf[j][e]), wcs[e], p);
    if (dg < LDIM) p = fmaf(labels[(size_t)id * LDIM + dg], va, p);
    m[j] = p;
  }
#pragma unroll
  for (int s = 1; s < 16; s <<= 1) {
#pragma unroll
    for (int j = 0; j < 8; ++j) m[j] += __shfl_xor(m[j], s);
  }
  float mx = m[0];
#pragma unroll
  for (int j = 1; j < 8; ++j) mx = fmaxf(mx, m[j]);
  mx = fmaxf(mx, __shfl_xor(mx, 16));
  mx = fmaxf(mx, __shfl_xor(mx, 32));
  float ssum = 0.f;
#pragma unroll
  for (int j = 0; j < 8; ++j) {
    m[j] = __expf(m[j] - mx);
    ssum += m[j];
  }
  ssum += __shfl_xor(ssum, 16);
  ssum += __shfl_xor(ssum, 32);
  const float scale = 1.f / (ssum * (float)KNBR);
  float pn[8];
#pragma unroll
  for (int e = 0; e < 8; ++e) pn[e] = 0.f;
#pragma unroll
  for (int j = 0; j < 8; ++j) {
#pragma unroll
    for (int e = 0; e < 8; ++e) pn[e] = fmaf(m[j], hf[j][e], pn[e]);
  }
#pragma unroll
  for (int e = 0; e < 8; ++e) {
    pn[e] += __shfl_xor(pn[e], 16);
    pn[e] += __shfl_xor(pn[e], 32);
  }
  if (kg == 0) {
    const float* srow = self0 + (size_t)n * OUT_F + dg * 8;
    float* orow = out + (size_t)n * OUT_F + dg * 8;
    f32x4 o0, o1;
#pragma unroll
    for (int e = 0; e < 4; ++e)
      o0[e] = (srow[e] + pn[e] * scale) * 0.5f + out_bias[dg * 8 + e];
#pragma unroll
    for (int e = 0; e < 4; ++e)
      o1[e] = (srow[4 + e] + pn[4 + e] * scale) * 0.5f + out_bias[dg * 8 + 4 + e];
    *(f32x4*)orow = o0;
    *(f32x4*)(orow + 4) = o1;
  }
  if (kg == 1 && dg < LDIM)
    out[OUT_CENT + (size_t)n * LDIM + dg] = labels[(size_t)n * LDIM + dg];
  if (kg == 2 && dg < LDIM)
    out[OUT_LORI + (size_t)n * LDIM + dg] = labels_ori[(size_t)n * LDIM + dg];
}

// ---------------------------------------------------------------------------
extern "C" void kernel_launch(void* const* d_in, const int* in_sizes, int n_in,
                              void* d_out, int out_size, void* d_ws, size_t ws_size,
                              hipStream_t stream) {
  const float* feat       = (const float*)d_in[0];
  const float* labels     = (const float*)d_in[1];
  const float* labels_ori = (const float*)d_in[2];
  const float* label_rela = (const float*)d_in[3];
  const float* W_neigh    = (const float*)d_in[4];
  const float* b_neigh    = (const float*)d_in[5];
  const float* W_self     = (const float*)d_in[6];
  const float* b_self     = (const float*)d_in[7];
  const float* W_attn     = (const float*)d_in[8];
  // d_in[9] = b_attn (constant under softmax -> unused)
  const float* fW         = (const float*)d_in[10];
  const float* eps        = (const float*)d_in[11];
  const float* out_bias   = (const float*)d_in[12];
  const int*   nbr_idx    = (const int*)d_in[13];

  float* wsf = (float*)d_ws;
  float* out = (float*)d_out;

  float*  w_comb = wsf + WS_WCOMB;
  ushort* Bn     = (ushort*)(wsf + WS_BN);
  ushort* Bsf    = (ushort*)(wsf + WS_BS);
  ushort* h_src  = (ushort*)(wsf + WS_HSRC);
  float*  self0  = wsf + WS_SELF0;

  prep_kernel<<<384, 256, 0, stream>>>(W_attn, fW, W_neigh, W_self, w_comb, Bn, Bsf);
  fused_gemm<<<NB_BIG + NB_SELF, 256, 0, stream>>>(feat, Bn, Bsf, b_neigh, b_self, h_src, self0);
  attn_kernel<<<(N_DST / 4), 256, 0, stream>>>(labels, labels_ori, label_rela, nbr_idx,
                                               h_src, self0, w_comb, eps, out_bias, out);
}

// Round 5
// 59.628 us; speedup vs baseline: 2.5276x; 1.1027x over previous
//
#include <hip/hip_runtime.h>
#include <hip/hip_bf16.h>

#define N_SRC 50000
#define N_DST 10000
#define KNBR  32
#define IN_F  256
#define OUT_F 128
#define LDIM  10
#define ATTN_OUT 1024
#define NB_BIG  782   // ceil(50000/64)
#define NB_SELF 157   // ceil(10000/64)

using f32x4 = __attribute__((ext_vector_type(4))) float;
using s16x8 = __attribute__((ext_vector_type(8))) short;

// Output layout (floats): rst (N_DST*128) | cent_l (N_DST*10) | labels_ori[:N_DST] (N_DST*10)
#define OUT_CENT (N_DST*OUT_F)
#define OUT_LORI (N_DST*OUT_F + N_DST*LDIM)

// Workspace float offsets
#define WS_WCOMB 0                                   // 128 floats
#define WS_BN    128                                 // 32768 ushort = 16384 floats
#define WS_BS    (128 + 16384)                       // 32768 ushort
#define WS_HSRC  (128 + 32768)                       // N_SRC*128 ushort = 3.2M floats
#define WS_SELF0 (128 + 32768 + (N_SRC*OUT_F/2))     // N_DST*128 floats
#define WS_SCORE (WS_SELF0 + N_DST*OUT_F)            // N_SRC floats

__device__ __forceinline__ ushort f2bf(float x) {
  __hip_bfloat16 h = __float2bfloat16(x);
  return *reinterpret_cast<ushort*>(&h);
}

// ---------------------------------------------------------------------------
// prep: blocks 0..127   -> w_comb[j] = sum_i W_attn[j,i]*fW[i]  (h_act part)
//       blocks 128..255 -> W_neigh fp32 -> bf16 subtiled [k/8][n][k&7]
//       blocks 256..383 -> W_self  same
// ---------------------------------------------------------------------------
__global__ __launch_bounds__(256) void prep_kernel(
    const float* __restrict__ W_attn, const float* __restrict__ fW,
    const float* __restrict__ W_neigh, const float* __restrict__ W_self,
    float* __restrict__ w_comb, ushort* __restrict__ Bn, ushort* __restrict__ Bs) {
  const int b = blockIdx.x;
  const int t = threadIdx.x;
  if (b < 128) {
    __shared__ float red[256];
    float s = 0.f;
#pragma unroll
    for (int i = 0; i < 4; ++i) {
      int o = t + i * 256;
      s += W_attn[(size_t)b * ATTN_OUT + o] * fW[o];
    }
    red[t] = s;
    __syncthreads();
    for (int st = 128; st > 0; st >>= 1) {
      if (t < st) red[t] += red[t + st];
      __syncthreads();
    }
    if (t == 0) w_comb[b] = red[0];
  } else if (b < 256) {
    int k = 2 * (b - 128) + (t >> 7);
    int n = t & 127;
    float x = W_neigh[(size_t)k * OUT_F + n];
    Bn[(k >> 3) * 1024 + n * 8 + (k & 7)] = f2bf(x);
  } else {
    int k = 2 * (b - 256) + (t >> 7);
    int n = t & 127;
    float x = W_self[(size_t)k * OUT_F + n];
    Bs[(k >> 3) * 1024 + n * 8 + (k & 7)] = f2bf(x);
  }
}

// ---------------------------------------------------------------------------
// MFMA GEMM body, no LDS. Tile 64 rows/block, wave = 16 rows. A loaded in
// two 8x16B batches (araw live range 32 regs, VGPR<=128 via launch_bounds).
// Neigh path additionally emits per-row attention score
// score_f[r] = dot(leaky(h_r), w_comb) in the epilogue (row-local!).
// ---------------------------------------------------------------------------
template<bool OUT_BF16>
__device__ __forceinline__ void gemm_body(
    const float* __restrict__ A, const ushort* __restrict__ Bp,
    const float* __restrict__ bias, const float* __restrict__ w_comb,
    void* __restrict__ C, float* __restrict__ score_f, int M, int m0) {
  const int t = threadIdx.x;
  const int wv = t >> 6, ln = t & 63;
  const int dg = ln & 15, kg = ln >> 4;
  int r = m0 + wv * 16 + dg;
  r = r < M ? r : M - 1;                    // branchless clamp: loads always valid
  const float* arow = &A[(size_t)r * IN_F];

  s16x8 afr[8];
#pragma unroll
  for (int half = 0; half < 2; ++half) {
    f32x4 araw[8];
#pragma unroll
    for (int k0 = 0; k0 < 4; ++k0) {
      const f32x4* ap = (const f32x4*)&arow[(half * 4 + k0) * 32 + kg * 8];
      araw[2 * k0]     = ap[0];
      araw[2 * k0 + 1] = ap[1];
    }
#pragma unroll
    for (int k0 = 0; k0 < 4; ++k0) {
      s16x8 f;
      f[0] = (short)f2bf(araw[2*k0][0]); f[1] = (short)f2bf(araw[2*k0][1]);
      f[2] = (short)f2bf(araw[2*k0][2]); f[3] = (short)f2bf(araw[2*k0][3]);
      f[4] = (short)f2bf(araw[2*k0+1][0]); f[5] = (short)f2bf(araw[2*k0+1][1]);
      f[6] = (short)f2bf(araw[2*k0+1][2]); f[7] = (short)f2bf(araw[2*k0+1][3]);
      afr[half * 4 + k0] = f;
    }
  }

  f32x4 acc[8];
#pragma unroll
  for (int ct = 0; ct < 8; ++ct) acc[ct] = (f32x4){0.f, 0.f, 0.f, 0.f};
#pragma unroll
  for (int k0 = 0; k0 < 8; ++k0) {
    const ushort* bb = Bp + (k0 * 4 + kg) * 1024 + dg * 8;
#pragma unroll
    for (int ct = 0; ct < 8; ++ct) {
      s16x8 bfr = *reinterpret_cast<const s16x8*>(bb + ct * 128);
      acc[ct] = __builtin_amdgcn_mfma_f32_16x16x32_bf16(afr[k0], bfr, acc[ct], 0, 0, 0);
    }
  }

  // Epilogue. D layout: col = ct*16+dg, row = m0+wv*16+kg*4+e (HW-verified m89).
  float sc[4] = {0.f, 0.f, 0.f, 0.f};
#pragma unroll
  for (int ct = 0; ct < 8; ++ct) {
    int col = ct * 16 + dg;
    float bb = bias[col];
    float wc = OUT_BF16 ? w_comb[col] : 0.f;
#pragma unroll
    for (int e = 0; e < 4; ++e) {
      int rr = m0 + wv * 16 + kg * 4 + e;
      float v = acc[ct][e] + bb;
      if (OUT_BF16) {
        sc[e] = fmaf(fmaxf(v, 0.1f * v), wc, sc[e]);
        if (rr < M) ((ushort*)C)[(size_t)rr * OUT_F + col] = f2bf(v);
      } else {
        if (rr < M) ((float*)C)[(size_t)rr * OUT_F + col] = v;
      }
    }
  }
  if (OUT_BF16) {
    // reduce score partials across the 16 dg lanes (rows are per (kg,e))
#pragma unroll
    for (int s = 1; s < 16; s <<= 1) {
#pragma unroll
      for (int e = 0; e < 4; ++e) sc[e] += __shfl_xor(sc[e], s);
    }
    if (dg == 0) {
#pragma unroll
      for (int e = 0; e < 4; ++e) {
        int rr = m0 + wv * 16 + kg * 4 + e;
        if (rr < M) score_f[rr] = sc[e];
      }
    }
  }
}

__global__ __launch_bounds__(256, 4) void fused_gemm(
    const float* __restrict__ A,
    const ushort* __restrict__ Bn, const ushort* __restrict__ Bs,
    const float* __restrict__ bias_n, const float* __restrict__ bias_s,
    const float* __restrict__ w_comb,
    ushort* __restrict__ hsrc, float* __restrict__ self0, float* __restrict__ score_f) {
  if (blockIdx.x < NB_BIG)
    gemm_body<true>(A, Bn, bias_n, w_comb, (void*)hsrc, score_f, N_SRC, blockIdx.x * 64);
  else
    gemm_body<false>(A, Bs, bias_s, w_comb, (void*)self0, score_f, N_DST, (blockIdx.x - NB_BIG) * 64);
}

// ---------------------------------------------------------------------------
// attn: one wave per dst node. Lane (dg=l&15, kg=l>>4). Score path is now a
// 4B gather of precomputed score_f (dg==0 lanes) + label-sim partials; the
// packed h gathers (uint4, kept packed -> low VGPR) feed only PV.
// ---------------------------------------------------------------------------
__global__ __launch_bounds__(256, 4) void attn_kernel(
    const float* __restrict__ labels, const float* __restrict__ labels_ori,
    const float* __restrict__ label_rela, const int* __restrict__ nbr_idx,
    const ushort* __restrict__ hsrc, const float* __restrict__ self0,
    const float* __restrict__ score_f, const float* __restrict__ eps_p,
    const float* __restrict__ out_bias, float* __restrict__ out) {
  const int t = threadIdx.x;
  const int wv = t >> 6, ln = t & 63;
  const int n = blockIdx.x * 4 + wv;
  const int dg = ln & 15, kg = ln >> 4;

  const float eps = eps_p[0];
  const float om = 1.f - eps;

  // va[dg] = eps * sum_b rela[dg][b]*cent_l[b]
  float va = 0.f;
  if (dg < LDIM) {
#pragma unroll
    for (int b = 0; b < LDIM; ++b)
      va += label_rela[dg * LDIM + b] * labels[(size_t)n * LDIM + b];
    va *= eps;
  }

  const int* irow = nbr_idx + (size_t)n * KNBR;
  int ids[8];
  uint4 hv[8];
#pragma unroll
  for (int j = 0; j < 8; ++j) {
    ids[j] = irow[kg * 8 + j];
    hv[j] = *(const uint4*)(hsrc + (size_t)ids[j] * OUT_F + dg * 8);
  }
  // merge partials: dg==0 carries the precomputed feat-sim score; dg<10 the label sim
  float m[8];
#pragma unroll
  for (int j = 0; j < 8; ++j) {
    float sp = 0.f;
    if (dg == 0) sp = om * score_f[ids[j]];
    if (dg < LDIM) sp = fmaf(labels[(size_t)ids[j] * LDIM + dg], va, sp);
    m[j] = sp;
  }
#pragma unroll
  for (int s = 1; s < 16; s <<= 1) {
#pragma unroll
    for (int j = 0; j < 8; ++j) m[j] += __shfl_xor(m[j], s);
  }
  // softmax over all 32 neighbors
  float mx = m[0];
#pragma unroll
  for (int j = 1; j < 8; ++j) mx = fmaxf(mx, m[j]);
  mx = fmaxf(mx, __shfl_xor(mx, 16));
  mx = fmaxf(mx, __shfl_xor(mx, 32));
  float ssum = 0.f;
#pragma unroll
  for (int j = 0; j < 8; ++j) {
    m[j] = __expf(m[j] - mx);
    ssum += m[j];
  }
  ssum += __shfl_xor(ssum, 16);
  ssum += __shfl_xor(ssum, 32);
  const float scale = 1.f / (ssum * (float)KNBR);
  // PV: unpack at use, partial over this kg's 8 neighbors
  float pn[8];
#pragma unroll
  for (int e = 0; e < 8; ++e) pn[e] = 0.f;
#pragma unroll
  for (int j = 0; j < 8; ++j) {
    float a = m[j];
    pn[0] = fmaf(a, __uint_as_float(hv[j].x << 16), pn[0]);
    pn[1] = fmaf(a, __uint_as_float(hv[j].x & 0xffff0000u), pn[1]);
    pn[2] = fmaf(a, __uint_as_float(hv[j].y << 16), pn[2]);
    pn[3] = fmaf(a, __uint_as_float(hv[j].y & 0xffff0000u), pn[3]);
    pn[4] = fmaf(a, __uint_as_float(hv[j].z << 16), pn[4]);
    pn[5] = fmaf(a, __uint_as_float(hv[j].z & 0xffff0000u), pn[5]);
    pn[6] = fmaf(a, __uint_as_float(hv[j].w << 16), pn[6]);
    pn[7] = fmaf(a, __uint_as_float(hv[j].w & 0xffff0000u), pn[7]);
  }
#pragma unroll
  for (int e = 0; e < 8; ++e) {
    pn[e] += __shfl_xor(pn[e], 16);
    pn[e] += __shfl_xor(pn[e], 32);
  }
  if (kg == 0) {
    const float* srow = self0 + (size_t)n * OUT_F + dg * 8;
    float* orow = out + (size_t)n * OUT_F + dg * 8;
    f32x4 o0, o1;
#pragma unroll
    for (int e = 0; e < 4; ++e)
      o0[e] = (srow[e] + pn[e] * scale) * 0.5f + out_bias[dg * 8 + e];
#pragma unroll
    for (int e = 0; e < 4; ++e)
      o1[e] = (srow[4 + e] + pn[4 + e] * scale) * 0.5f + out_bias[dg * 8 + 4 + e];
    *(f32x4*)orow = o0;
    *(f32x4*)(orow + 4) = o1;
  }
  if (kg == 1 && dg < LDIM)
    out[OUT_CENT + (size_t)n * LDIM + dg] = labels[(size_t)n * LDIM + dg];
  if (kg == 2 && dg < LDIM)
    out[OUT_LORI + (size_t)n * LDIM + dg] = labels_ori[(size_t)n * LDIM + dg];
}

// ---------------------------------------------------------------------------
extern "C" void kernel_launch(void* const* d_in, const int* in_sizes, int n_in,
                              void* d_out, int out_size, void* d_ws, size_t ws_size,
                              hipStream_t stream) {
  const float* feat       = (const float*)d_in[0];
  const float* labels     = (const float*)d_in[1];
  const float* labels_ori = (const float*)d_in[2];
  const float* label_rela = (const float*)d_in[3];
  const float* W_neigh    = (const float*)d_in[4];
  const float* b_neigh    = (const float*)d_in[5];
  const float* W_self     = (const float*)d_in[6];
  const float* b_self     = (const float*)d_in[7];
  const float* W_attn     = (const float*)d_in[8];
  // d_in[9] = b_attn (constant under softmax -> unused)
  const float* fW         = (const float*)d_in[10];
  const float* eps        = (const float*)d_in[11];
  const float* out_bias   = (const float*)d_in[12];
  const int*   nbr_idx    = (const int*)d_in[13];

  float* wsf = (float*)d_ws;
  float* out = (float*)d_out;

  float*  w_comb  = wsf + WS_WCOMB;
  ushort* Bn      = (ushort*)(wsf + WS_BN);
  ushort* Bsf     = (ushort*)(wsf + WS_BS);
  ushort* h_src   = (ushort*)(wsf + WS_HSRC);
  float*  self0   = wsf + WS_SELF0;
  float*  score_f = wsf + WS_SCORE;

  prep_kernel<<<384, 256, 0, stream>>>(W_attn, fW, W_neigh, W_self, w_comb, Bn, Bsf);
  fused_gemm<<<NB_BIG + NB_SELF, 256, 0, stream>>>(feat, Bn, Bsf, b_neigh, b_self,
                                                   w_comb, h_src, self0, score_f);
  attn_kernel<<<(N_DST / 4), 256, 0, stream>>>(labels, labels_ori, label_rela, nbr_idx,
                                               h_src, self0, score_f, eps, out_bias, out);
}